// Round 1
// baseline (191.330 us; speedup 1.0000x reference)
//
#include <hip/hip_runtime.h>

#define L 2048
#define HD 1024   // H*D
#define NB 8      // batch
#define BM 128
#define BN 128
#define BK 32
#define LDP 40    // padded LDS row length in bf16 elements (80 B, 16B-aligned)

using f32x4 = __attribute__((ext_vector_type(4))) float;
using s16x8 = __attribute__((ext_vector_type(8))) short;
using s16x4 = __attribute__((ext_vector_type(4))) short;

__device__ __forceinline__ short f2bf(float f) {
    unsigned u = __float_as_uint(f);
    u += 0x7fffu + ((u >> 16) & 1u);   // round-to-nearest-even
    return (short)(u >> 16);
}

__global__ __launch_bounds__(256) void pb_gemm(const float* __restrict__ v,
                                               const float* __restrict__ w,
                                               float* __restrict__ out) {
    __shared__ __align__(16) short Asm[BM * LDP];
    __shared__ __align__(16) short Bsm[BN * LDP];

    const int cm = blockIdx.x;       // 0..7   (column tile over HD)
    const int jm = blockIdx.y;       // 0..15  (row tile over L)
    const int n  = blockIdx.z;       // 0..7   (batch)
    const int j0 = jm * BM;
    const int c0 = cm * BN;
    const int t  = threadIdx.x;
    const int lane = t & 63;
    const int wid  = t >> 6;
    const int wr = wid >> 1, wc = wid & 1;   // 2x2 wave grid, 64x64 each
    const int fr = lane & 15;                // row (A) / col (B,C)
    const int fk = lane >> 4;                // k-chunk 0..3

    const float* vn  = v   + (size_t)n * L * HD;
    float*       outn = out + (size_t)n * L * HD;

    f32x4 acc[4][4] = {};

    // staging assignments
    const int aj = t & 127;   // A row j (0..127)
    const int ah = t >> 7;    // A k-half (16 elems each)
    const int bc = t & 127;   // B row c (0..127)
    const int bh = t >> 7;    // B quad parity

    for (int kk = 0; kk < L / BK; ++kk) {
        const int l0 = kk * BK;

        // ---- stage A tile: bias[j0+aj][l0 + ah*16 + i] = w[|j-l|] (bf16) ----
        {
            const int jg = j0 + aj;
            s16x8 p0, p1;
            #pragma unroll
            for (int i = 0; i < 8; ++i) {
                int lg = l0 + ah * 16 + i;
                int d = jg - lg; d = d < 0 ? -d : d;
                p0[i] = f2bf(w[d]);
            }
            #pragma unroll
            for (int i = 0; i < 8; ++i) {
                int lg = l0 + ah * 16 + 8 + i;
                int d = jg - lg; d = d < 0 ? -d : d;
                p1[i] = f2bf(w[d]);
            }
            *(s16x8*)&Asm[aj * LDP + ah * 16]     = p0;
            *(s16x8*)&Asm[aj * LDP + ah * 16 + 8] = p1;
        }

        // ---- stage B tile transposed: Bsm[c][k] = bf16(v[n][l0+k][c0+c]) ----
        {
            #pragma unroll
            for (int g = 0; g < 4; ++g) {
                const int q = bh + g * 2;    // 0..7, 4 k's each
                s16x4 pk;
                #pragma unroll
                for (int i = 0; i < 4; ++i) {
                    pk[i] = f2bf(vn[(size_t)(l0 + q * 4 + i) * HD + c0 + bc]);
                }
                *(s16x4*)&Bsm[bc * LDP + q * 4] = pk;
            }
        }

        __syncthreads();

        s16x8 af[4], bfr[4];
        #pragma unroll
        for (int m = 0; m < 4; ++m)
            af[m] = *(const s16x8*)&Asm[(wr * 64 + m * 16 + fr) * LDP + fk * 8];
        #pragma unroll
        for (int nf = 0; nf < 4; ++nf)
            bfr[nf] = *(const s16x8*)&Bsm[(wc * 64 + nf * 16 + fr) * LDP + fk * 8];

        #pragma unroll
        for (int m = 0; m < 4; ++m) {
            #pragma unroll
            for (int nf = 0; nf < 4; ++nf) {
                acc[m][nf] = __builtin_amdgcn_mfma_f32_16x16x32_bf16(
                    af[m], bfr[nf], acc[m][nf], 0, 0, 0);
            }
        }

        __syncthreads();
    }

    // ---- epilogue: C/D layout col=lane&15, row=(lane>>4)*4+r ----
    #pragma unroll
    for (int m = 0; m < 4; ++m) {
        const int row = j0 + wr * 64 + m * 16 + fk * 4;
        #pragma unroll
        for (int nf = 0; nf < 4; ++nf) {
            const int col = c0 + wc * 64 + nf * 16 + fr;
            #pragma unroll
            for (int r = 0; r < 4; ++r)
                outn[(size_t)(row + r) * HD + col] = acc[m][nf][r];
        }
    }
}

__global__ __launch_bounds__(256) void pb_z(const float* __restrict__ w,
                                            float* __restrict__ z) {
    __shared__ float ws[L];
    for (int i = threadIdx.x; i < L; i += 256) ws[i] = w[i];
    __syncthreads();
    const int j = blockIdx.x * 256 + threadIdx.x;
    float s = 0.f;
    for (int l = 0; l < L; ++l) {
        int d = j - l; d = d < 0 ? -d : d;
        s += ws[d];
    }
    z[j] = s;
}

extern "C" void kernel_launch(void* const* d_in, const int* in_sizes, int n_in,
                              void* d_out, int out_size, void* d_ws, size_t ws_size,
                              hipStream_t stream) {
    const float* v = (const float*)d_in[0];
    const float* w = (const float*)d_in[1];
    float* out = (float*)d_out;

    dim3 grid(HD / BN, L / BM, NB);   // 8 x 16 x 8 = 1024 blocks
    pb_gemm<<<grid, 256, 0, stream>>>(v, w, out);

    pb_z<<<L / 256, 256, 0, stream>>>(w, out + (size_t)NB * L * HD);
}

// Round 2
// 179.386 us; speedup vs baseline: 1.0666x; 1.0666x over previous
//
#include <hip/hip_runtime.h>
#include <hip/hip_bf16.h>

#define L 2048
#define HD 1024   // H*D
#define NB 8      // batch
#define BM 128
#define BN 128
#define BK 32
#define LDPB 36   // B LDS row stride (bf16 elems): stride 18 dwords -> conflict-free writes+reads
#define PROW 4096 // p8 row length in elems (indices 0..4094 valid, padded)

using f32x4 = __attribute__((ext_vector_type(4))) float;
using s16x8 = __attribute__((ext_vector_type(8))) short;
using s16x4 = __attribute__((ext_vector_type(4))) short;

__device__ __forceinline__ short f2bf(float f) {
    __hip_bfloat16 h = __float2bfloat16(f);   // RNE; compiler can pair into v_cvt_pk_bf16_f32
    short s;
    __builtin_memcpy(&s, &h, 2);
    return s;
}

__device__ __forceinline__ void gload_lds16(const void* g, void* l) {
    __builtin_amdgcn_global_load_lds(
        (const __attribute__((address_space(1))) unsigned int*)g,
        (__attribute__((address_space(3))) unsigned int*)l, 16, 0, 0);
}

// ---- prep: p8[s][x] = bf16(p[x+s]), p[k] = w[|k-2047|], k in [0,4094] ----
__global__ __launch_bounds__(256) void pb_prep(const float* __restrict__ w,
                                               short* __restrict__ p8) {
    int idx = blockIdx.x * 256 + threadIdx.x;   // 8*PROW total
    int s = idx >> 12;                          // PROW = 4096
    int x = idx & (PROW - 1);
    int k = x + s;
    short val = 0;
    if (k <= 4094) {
        int d = k - 2047; d = d < 0 ? -d : d;
        val = f2bf(w[d]);
    }
    p8[idx] = val;
}

__global__ __launch_bounds__(256) void pb_gemm(const float* __restrict__ v,
                                               const short* __restrict__ p8,
                                               float* __restrict__ out) {
    __shared__ __align__(16) short Asm[BM * BK];     // 8 KB, linear (gload_lds dest)
    __shared__ __align__(16) short Bsm[BN * LDPB];   // 9 KB

    const int cm = blockIdx.x;       // 0..7
    const int jm = blockIdx.y;       // 0..15
    const int n  = blockIdx.z;       // 0..7
    const int j0 = jm * BM;
    const int c0 = cm * BN;
    const int t  = threadIdx.x;
    const int lane = t & 63;
    const int wid  = t >> 6;
    const int wr = wid >> 1, wc = wid & 1;
    const int fr = lane & 15;
    const int fk = lane >> 4;

    const float* vn   = v   + (size_t)n * L * HD;
    float*       outn = out + (size_t)n * L * HD;

    // ---- A staging setup: 2 chunks/thread via global_load_lds ----
    // chunk cid -> LDS bytes [cid*16, +16) = A[row=cid>>2][ (hs=cid&3) slot ]
    // slot hs holds data half h = hs ^ (row&3)  (read-side XOR swizzle)
    const short* asrc0;
    const short* asrc1;
    {
        int cid = wid * 128 + lane;
        int row = cid >> 2, hs = cid & 3, h = hs ^ (row & 3);
        int q = 2047 + h * 8 - j0 - row;          // l0 = 0
        int s = q & 7;
        asrc0 = p8 + s * PROW + (q - s);
        cid += 64;
        row = cid >> 2; hs = cid & 3; h = hs ^ (row & 3);
        q = 2047 + h * 8 - j0 - row;
        s = q & 7;
        asrc1 = p8 + s * PROW + (q - s);
    }
    char* abase0 = (char*)Asm + wid * 2048;       // wave-uniform dest bases
    char* abase1 = abase0 + 1024;

    // ---- B staging setup ----
    const int bc  = t & 127;        // column in tile
    const int bq0 = t >> 7;         // 0/1
    const float* vcol = vn + c0 + bc;

    f32x4 acc[4][4] = {};

    for (int kk = 0; kk < L / BK; ++kk) {
        // A: async global->LDS (16 B x 2), sources advance 32 elems/step
        gload_lds16(asrc0, abase0);
        gload_lds16(asrc1, abase1);
        asrc0 += BK;
        asrc1 += BK;

        // B: Bsm[c][k] = bf16(v[l0+k][c0+c])
        const float* vk = vcol + (size_t)(kk * BK) * HD;
        #pragma unroll
        for (int g = 0; g < 4; ++g) {
            const int q = bq0 + g * 2;   // k-quad
            s16x4 pk;
            #pragma unroll
            for (int i = 0; i < 4; ++i)
                pk[i] = f2bf(vk[(size_t)(q * 4 + i) * HD]);
            *(s16x4*)&Bsm[bc * LDPB + q * 4] = pk;
        }

        __syncthreads();   // drains vmcnt (gload_lds) + lgkm

        s16x8 af[4], bfr[4];
        #pragma unroll
        for (int m = 0; m < 4; ++m) {
            const int r = wr * 64 + m * 16 + fr;
            const int fkp = fk ^ (r & 3);
            af[m] = *(const s16x8*)&Asm[r * BK + fkp * 8];
        }
        #pragma unroll
        for (int nf = 0; nf < 4; ++nf) {
            const int rc = wc * 64 + nf * 16 + fr;
            const short* bp = &Bsm[rc * LDPB + fk * 8];
            s16x4 lo = *(const s16x4*)bp;
            s16x4 hi = *(const s16x4*)(bp + 4);
            s16x8 b;
            b[0] = lo[0]; b[1] = lo[1]; b[2] = lo[2]; b[3] = lo[3];
            b[4] = hi[0]; b[5] = hi[1]; b[6] = hi[2]; b[7] = hi[3];
            bfr[nf] = b;
        }

        #pragma unroll
        for (int m = 0; m < 4; ++m)
            #pragma unroll
            for (int nf = 0; nf < 4; ++nf)
                acc[m][nf] = __builtin_amdgcn_mfma_f32_16x16x32_bf16(
                    af[m], bfr[nf], acc[m][nf], 0, 0, 0);

        __syncthreads();
    }

    // ---- epilogue: C/D layout col=lane&15, row=(lane>>4)*4+r ----
    #pragma unroll
    for (int m = 0; m < 4; ++m) {
        const int row = j0 + wr * 64 + m * 16 + fk * 4;
        #pragma unroll
        for (int nf = 0; nf < 4; ++nf) {
            const int col = c0 + wc * 64 + nf * 16 + fr;
            #pragma unroll
            for (int r = 0; r < 4; ++r)
                outn[(size_t)(row + r) * HD + col] = acc[m][nf][r];
        }
    }
}

__global__ __launch_bounds__(256) void pb_z(const float* __restrict__ w,
                                            float* __restrict__ z) {
    __shared__ float ws[L];
    for (int i = threadIdx.x; i < L; i += 256) ws[i] = w[i];
    __syncthreads();
    const int j = blockIdx.x * 256 + threadIdx.x;
    float s = 0.f;
    for (int l = 0; l < L; ++l) {
        int d = j - l; d = d < 0 ? -d : d;
        s += ws[d];
    }
    z[j] = s;
}

extern "C" void kernel_launch(void* const* d_in, const int* in_sizes, int n_in,
                              void* d_out, int out_size, void* d_ws, size_t ws_size,
                              hipStream_t stream) {
    const float* v = (const float*)d_in[0];
    const float* w = (const float*)d_in[1];
    float* out = (float*)d_out;
    short* p8 = (short*)d_ws;   // 8 * 4096 * 2 B = 64 KB

    pb_prep<<<(8 * PROW) / 256, 256, 0, stream>>>(w, p8);

    dim3 grid(HD / BN, L / BM, NB);   // 8 x 16 x 8 = 1024 blocks
    pb_gemm<<<grid, 256, 0, stream>>>(v, p8, out);

    pb_z<<<L / 256, 256, 0, stream>>>(w, out + (size_t)NB * L * HD);
}

// Round 3
// 161.504 us; speedup vs baseline: 1.1847x; 1.1107x over previous
//
#include <hip/hip_runtime.h>
#include <hip/hip_bf16.h>

#define L 2048
#define HD 1024   // H*D
#define NB 8      // batch
#define BM 128
#define BN 128
#define BK 32
#define LDPB 36   // fallback kernel B stride
#define PROW 4096 // p8 row length

using f32x4 = __attribute__((ext_vector_type(4))) float;
using fl4   = __attribute__((ext_vector_type(4))) float;
using s16x8 = __attribute__((ext_vector_type(8))) short;
using s16x4 = __attribute__((ext_vector_type(4))) short;

__device__ __forceinline__ short f2bf(float f) {
    __hip_bfloat16 h = __float2bfloat16(f);
    short s;
    __builtin_memcpy(&s, &h, 2);
    return s;
}

__device__ __forceinline__ void gload_lds16(const void* g, void* l) {
    __builtin_amdgcn_global_load_lds(
        (const __attribute__((address_space(1))) unsigned int*)g,
        (__attribute__((address_space(3))) unsigned int*)l, 16, 0, 0);
}

// chunk id o -> (row r, k-quarter h) with 8-slot XOR swizzle baked in:
// o = g*8 + s ; u = s ^ (g&7) ; r = 2g + (u>>2) ; h = u&3
__device__ __forceinline__ void chunk_rh(int o, int& r, int& h) {
    int g = o >> 3, s = o & 7, u = s ^ (g & 7);
    r = 2 * g + (u >> 2);
    h = u & 3;
}

// ---- p8[s][x] = bf16(p[x+s]), p[k] = w[|k-2047|] ----
__global__ __launch_bounds__(256) void pb_prep(const float* __restrict__ w,
                                               short* __restrict__ p8) {
    int idx = blockIdx.x * 256 + threadIdx.x;
    int s = idx >> 12;
    int x = idx & (PROW - 1);
    int k = x + s;
    short val = 0;
    if (k <= 4094) {
        int d = k - 2047; d = d < 0 ? -d : d;
        val = f2bf(w[d]);
    }
    p8[idx] = val;
}

// ---- atile[jm][kk][o] : bias tiles, chunk-ordered, swizzle-baked ----
__global__ __launch_bounds__(256) void pb_atile(const short* __restrict__ p8,
                                                s16x8* __restrict__ atile) {
    const int kk = blockIdx.x;   // 0..63
    const int jm = blockIdx.y;   // 0..15
    const int j0 = jm * BM, l0 = kk * BK;
    const int t = threadIdx.x;
    #pragma unroll
    for (int i = 0; i < 2; ++i) {
        int o = i * 256 + t;
        int r, h; chunk_rh(o, r, h);
        int idx0 = 2047 + l0 + h * 8 - j0 - r;   // p-index of first elem
        int srow = idx0 & 7;
        s16x8 val = *(const s16x8*)(p8 + srow * PROW + (idx0 - srow));
        atile[(size_t)(jm * 64 + kk) * 512 + o] = val;
    }
}

// ---- vtile[n][cm][kk][o] : v transposed to [c][k] bf16, chunk-ordered ----
__global__ __launch_bounds__(256) void pb_vtile(const float* __restrict__ v,
                                                s16x8* __restrict__ vtile) {
    __shared__ __align__(16) short Ts[128 * 40];   // [c][k], pad to 40
    const int kk = blockIdx.x;    // 0..63
    const int cmB = blockIdx.y;   // 0..7
    const int n = blockIdx.z;
    const int l0 = kk * BK, c0 = cmB * BN;
    const int t = threadIdx.x;
    const float* vn = v + (size_t)n * L * HD;

    #pragma unroll
    for (int i = 0; i < 4; ++i) {
        int l = i * 8 + (t >> 5);
        int c4 = (t & 31) * 4;
        fl4 vv = *(const fl4*)&vn[(size_t)(l0 + l) * HD + c0 + c4];
        #pragma unroll
        for (int j = 0; j < 4; ++j)
            Ts[(c4 + j) * 40 + l] = f2bf(vv[j]);
    }
    __syncthreads();
    #pragma unroll
    for (int i = 0; i < 2; ++i) {
        int o = i * 256 + t;
        int r, h; chunk_rh(o, r, h);
        s16x8 val = *(const s16x8*)&Ts[r * 40 + h * 8];
        vtile[(size_t)((n * 8 + cmB) * 64 + kk) * 512 + o] = val;
    }
}

// ---- main GEMM: both operands pre-tiled, m97 structure ----
__global__ __launch_bounds__(256) void pb_gemm_fast(const s16x8* __restrict__ atile,
                                                    const s16x8* __restrict__ vtile,
                                                    float* __restrict__ out) {
    __shared__ __align__(16) short Asm[BM * BK];   // 8 KB
    __shared__ __align__(16) short Bsm[BN * BK];   // 8 KB

    const int cm = blockIdx.x;   // 0..7
    const int jm = blockIdx.y;   // 0..15
    const int n  = blockIdx.z;   // 0..7
    const int j0 = jm * BM;
    const int c0 = cm * BN;
    const int t  = threadIdx.x;
    const int lane = t & 63;
    const int wid  = t >> 6;
    const int wr = wid >> 1, wc = wid & 1;
    const int fr = lane & 15;
    const int fk = lane >> 4;

    const s16x8* asrc = atile + (size_t)(jm * 64) * 512 + wid * 128 + lane;
    const s16x8* bsrc = vtile + (size_t)((n * 8 + cm) * 64) * 512 + wid * 128 + lane;
    char* adst0 = (char*)Asm + wid * 2048;
    char* adst1 = adst0 + 1024;
    char* bdst0 = (char*)Bsm + wid * 2048;
    char* bdst1 = bdst0 + 1024;

    // K-invariant read byte-offsets (swizzle-aware)
    int aoff[4], boff[4];
    #pragma unroll
    for (int m = 0; m < 4; ++m) {
        int r = wr * 64 + m * 16 + fr;
        aoff[m] = (r >> 1) * 128 + ((((r & 1) * 4 + fk) ^ ((r >> 1) & 7)) * 16);
    }
    #pragma unroll
    for (int nf = 0; nf < 4; ++nf) {
        int rc = wc * 64 + nf * 16 + fr;
        boff[nf] = (rc >> 1) * 128 + ((((rc & 1) * 4 + fk) ^ ((rc >> 1) & 7)) * 16);
    }

    f32x4 acc[4][4] = {};

    for (int kk = 0; kk < L / BK; ++kk) {
        gload_lds16(asrc,      adst0);
        gload_lds16(asrc + 64, adst1);
        gload_lds16(bsrc,      bdst0);
        gload_lds16(bsrc + 64, bdst1);
        asrc += 512; bsrc += 512;

        __syncthreads();   // drains vmcnt -> tiles ready

        s16x8 af[4], bfr[4];
        #pragma unroll
        for (int m = 0; m < 4; ++m)
            af[m] = *(const s16x8*)((const char*)Asm + aoff[m]);
        #pragma unroll
        for (int nf = 0; nf < 4; ++nf)
            bfr[nf] = *(const s16x8*)((const char*)Bsm + boff[nf]);

        #pragma unroll
        for (int m = 0; m < 4; ++m)
            #pragma unroll
            for (int nf = 0; nf < 4; ++nf)
                acc[m][nf] = __builtin_amdgcn_mfma_f32_16x16x32_bf16(
                    af[m], bfr[nf], acc[m][nf], 0, 0, 0);

        __syncthreads();
    }

    float* outn = out + (size_t)n * L * HD;
    #pragma unroll
    for (int m = 0; m < 4; ++m) {
        const int row = j0 + wr * 64 + m * 16 + fk * 4;
        #pragma unroll
        for (int nf = 0; nf < 4; ++nf) {
            const int col = c0 + wc * 64 + nf * 16 + fr;
            #pragma unroll
            for (int r = 0; r < 4; ++r)
                outn[(size_t)(row + r) * HD + col] = acc[m][nf][r];
        }
    }
}

// ---- fallback (round-2 kernel), used if ws_size too small ----
__global__ __launch_bounds__(256) void pb_gemm_slow(const float* __restrict__ v,
                                                    const short* __restrict__ p8,
                                                    float* __restrict__ out) {
    __shared__ __align__(16) short Asm[BM * BK];
    __shared__ __align__(16) short Bsm[BN * LDPB];

    const int cm = blockIdx.x;
    const int jm = blockIdx.y;
    const int n  = blockIdx.z;
    const int j0 = jm * BM;
    const int c0 = cm * BN;
    const int t  = threadIdx.x;
    const int lane = t & 63;
    const int wid  = t >> 6;
    const int wr = wid >> 1, wc = wid & 1;
    const int fr = lane & 15;
    const int fk = lane >> 4;

    const float* vn   = v   + (size_t)n * L * HD;
    float*       outn = out + (size_t)n * L * HD;

    const short* asrc0;
    const short* asrc1;
    {
        int cid = wid * 128 + lane;
        int row = cid >> 2, hs = cid & 3, h = hs ^ (row & 3);
        int q = 2047 + h * 8 - j0 - row;
        int s = q & 7;
        asrc0 = p8 + s * PROW + (q - s);
        cid += 64;
        row = cid >> 2; hs = cid & 3; h = hs ^ (row & 3);
        q = 2047 + h * 8 - j0 - row;
        s = q & 7;
        asrc1 = p8 + s * PROW + (q - s);
    }
    char* abase0 = (char*)Asm + wid * 2048;
    char* abase1 = abase0 + 1024;

    const int bc  = t & 127;
    const int bq0 = t >> 7;
    const float* vcol = vn + c0 + bc;

    f32x4 acc[4][4] = {};

    for (int kk = 0; kk < L / BK; ++kk) {
        gload_lds16(asrc0, abase0);
        gload_lds16(asrc1, abase1);
        asrc0 += BK;
        asrc1 += BK;

        const float* vk = vcol + (size_t)(kk * BK) * HD;
        #pragma unroll
        for (int g = 0; g < 4; ++g) {
            const int q = bq0 + g * 2;
            s16x4 pk;
            #pragma unroll
            for (int i = 0; i < 4; ++i)
                pk[i] = f2bf(vk[(size_t)(q * 4 + i) * HD]);
            *(s16x4*)&Bsm[bc * LDPB + q * 4] = pk;
        }

        __syncthreads();

        s16x8 af[4], bfr[4];
        #pragma unroll
        for (int m = 0; m < 4; ++m) {
            const int r = wr * 64 + m * 16 + fr;
            const int fkp = fk ^ (r & 3);
            af[m] = *(const s16x8*)&Asm[r * BK + fkp * 8];
        }
        #pragma unroll
        for (int nf = 0; nf < 4; ++nf) {
            const int rc = wc * 64 + nf * 16 + fr;
            const short* bp = &Bsm[rc * LDPB + fk * 8];
            s16x4 lo = *(const s16x4*)bp;
            s16x4 hi = *(const s16x4*)(bp + 4);
            s16x8 b;
            b[0] = lo[0]; b[1] = lo[1]; b[2] = lo[2]; b[3] = lo[3];
            b[4] = hi[0]; b[5] = hi[1]; b[6] = hi[2]; b[7] = hi[3];
            bfr[nf] = b;
        }

        #pragma unroll
        for (int m = 0; m < 4; ++m)
            #pragma unroll
            for (int nf = 0; nf < 4; ++nf)
                acc[m][nf] = __builtin_amdgcn_mfma_f32_16x16x32_bf16(
                    af[m], bfr[nf], acc[m][nf], 0, 0, 0);

        __syncthreads();
    }

    #pragma unroll
    for (int m = 0; m < 4; ++m) {
        const int row = j0 + wr * 64 + m * 16 + fk * 4;
        #pragma unroll
        for (int nf = 0; nf < 4; ++nf) {
            const int col = c0 + wc * 64 + nf * 16 + fr;
            #pragma unroll
            for (int r = 0; r < 4; ++r)
                outn[(size_t)(row + r) * HD + col] = acc[m][nf][r];
        }
    }
}

__global__ __launch_bounds__(256) void pb_z(const float* __restrict__ w,
                                            float* __restrict__ z) {
    __shared__ float ws[L];
    for (int i = threadIdx.x; i < L; i += 256) ws[i] = w[i];
    __syncthreads();
    const int j = blockIdx.x * 256 + threadIdx.x;
    float s = 0.f;
    for (int l = 0; l < L; ++l) {
        int d = j - l; d = d < 0 ? -d : d;
        s += ws[d];
    }
    z[j] = s;
}

extern "C" void kernel_launch(void* const* d_in, const int* in_sizes, int n_in,
                              void* d_out, int out_size, void* d_ws, size_t ws_size,
                              hipStream_t stream) {
    const float* v = (const float*)d_in[0];
    const float* w = (const float*)d_in[1];
    float* out = (float*)d_out;

    short* p8 = (short*)d_ws;                                  // 64 KB
    const size_t P8_BYTES = 8 * PROW * sizeof(short);
    const size_t AT_BYTES = (size_t)16 * 64 * 512 * 16;        // 8 MB
    const size_t VT_BYTES = (size_t)8 * 8 * 64 * 512 * 16;     // 32 MB
    const size_t need = P8_BYTES + AT_BYTES + VT_BYTES;

    pb_prep<<<(8 * PROW) / 256, 256, 0, stream>>>(w, p8);

    dim3 grid(HD / BN, L / BM, NB);   // 8 x 16 x 8

    if (ws_size >= need) {
        s16x8* atile = (s16x8*)((char*)d_ws + P8_BYTES);
        s16x8* vtile = (s16x8*)((char*)d_ws + P8_BYTES + AT_BYTES);
        pb_atile<<<dim3(64, 16), 256, 0, stream>>>(p8, atile);
        pb_vtile<<<dim3(64, 8, 8), 256, 0, stream>>>(v, vtile);
        pb_gemm_fast<<<grid, 256, 0, stream>>>(atile, vtile, out);
    } else {
        pb_gemm_slow<<<grid, 256, 0, stream>>>(v, p8, out);
    }

    pb_z<<<L / 256, 256, 0, stream>>>(w, out + (size_t)NB * L * HD);
}

// Round 4
// 87.388 us; speedup vs baseline: 2.1894x; 1.8481x over previous
//
#include <hip/hip_runtime.h>
#include <hip/hip_bf16.h>

#define L 2048
#define HD 1024   // H*D
#define NB 8      // batch
#define NT 32     // K tiles of BK=64
#define PROW 4096 // p8 row length

using f32x4 = __attribute__((ext_vector_type(4))) float;
using fl4   = __attribute__((ext_vector_type(4))) float;
using s16x8 = __attribute__((ext_vector_type(8))) short;

__device__ __forceinline__ short f2bf(float f) {
    __hip_bfloat16 h = __float2bfloat16(f);
    short s;
    __builtin_memcpy(&s, &h, 2);
    return s;
}

__device__ __forceinline__ void gload_lds16(const void* g, void* l) {
    __builtin_amdgcn_global_load_lds(
        (const __attribute__((address_space(1))) unsigned int*)g,
        (__attribute__((address_space(3))) unsigned int*)l, 16, 0, 0);
}

// ---- p8[s][x] = bf16(p[x+s]), p[k] = w[|k-2047|] ----
__global__ __launch_bounds__(256) void pb_prep(const float* __restrict__ w,
                                               short* __restrict__ p8) {
    int idx = blockIdx.x * 256 + threadIdx.x;
    int s = idx >> 12;
    int x = idx & (PROW - 1);
    int k = x + s;
    short val = 0;
    if (k <= 4094) {
        int d = k - 2047; d = d < 0 ? -d : d;
        val = f2bf(w[d]);
    }
    p8[idx] = val;
}

// ---- vtile[n][cm][kk] : 2048 chunks of 16B in exact gemm-stage order ----
// chunk ci: nh=ci>>10; cih=ci&1023; seg=cih>>8; o=cih&255;
//   c = seg*64 + nh*32 + (o>>3); s = o&7; h = s ^ (c&7)
// content = bf16(v[n][kk*64 + h*8 + 0..7][cm*256 + c])
__global__ __launch_bounds__(256) void pb_vtile(const float* __restrict__ v,
                                                s16x8* __restrict__ vtile) {
    // Ts: (c,l) stored at c*64 + ((l>>3) ^ ((c>>2)&7))*8 + (l&7)  (slot swizzle)
    __shared__ __align__(16) short Ts[256 * 64];   // 32 KB
    const int kk = blockIdx.x, cm = blockIdx.y, n = blockIdx.z;
    const int l0 = kk * 64, c0 = cm * 256;
    const int t = threadIdx.x;
    const float* vn = v + (size_t)n * L * HD;

    #pragma unroll
    for (int i = 0; i < 16; ++i) {
        int unit = i * 256 + t;          // 4096 units = 64 l x 64 quads
        int l = unit >> 6, cq = unit & 63;
        fl4 x = *(const fl4*)&vn[(size_t)(l0 + l) * HD + c0 + cq * 4];
        int lsub = l & 7, lblk = l >> 3;
        #pragma unroll
        for (int j = 0; j < 4; ++j) {
            int c = cq * 4 + j;
            Ts[c * 64 + ((lblk ^ ((c >> 2) & 7)) << 3) + lsub] = f2bf(x[j]);
        }
    }
    __syncthreads();

    s16x8* outtile = vtile + ((size_t)((n * 4 + cm) * NT + kk)) * 2048;
    #pragma unroll
    for (int i2 = 0; i2 < 8; ++i2) {
        int ci = i2 * 256 + t;
        int nh = ci >> 10, cih = ci & 1023;
        int seg = cih >> 8, o = cih & 255;
        int c = seg * 64 + nh * 32 + (o >> 3), s = o & 7;
        int h = s ^ (c & 7);
        int slot = h ^ ((c >> 2) & 7);
        outtile[ci] = *(const s16x8*)&Ts[c * 64 + slot * 8];
    }
}

// ---- main GEMM: 256x256 tile, BK=64, 8 waves, 8-phase counted-vmcnt ----
__global__ __launch_bounds__(512, 2) void pb_gemm8(const short* __restrict__ p8,
                                                   const short* __restrict__ vtile,
                                                   float* __restrict__ out) {
    __shared__ __align__(16) short lds_[65536];  // 128 KB: 2 bufs x (A 32K | B 32K)

    const int bid = blockIdx.x;
    const int cmn = bid & 31;          // same (n,cm) for all 8 jm -> same XCD
    const int jm  = bid >> 5;
    const int cm  = cmn & 3;
    const int n   = cmn >> 2;
    const int j0 = jm * 256;
    const int c0 = cm * 256;

    const int t = threadIdx.x;
    const int lane = t & 63;
    const int w = t >> 6;              // wave 0..7
    const int wr = w >> 2, wc = w & 3; // 2 x 4 wave grid; wave tile 128x64
    const int fr = lane & 15, fk = lane >> 4;

    // K-invariant LDS read byte-offsets (ki=1 via ^64)
    int offA[8], offB[4];
    #pragma unroll
    for (int m = 0; m < 8; ++m) {
        int r = wr * 128 + m * 16 + fr;
        offA[m] = r * 128 + ((fk ^ (r & 7)) << 4);
    }
    #pragma unroll
    for (int nf = 0; nf < 4; ++nf) {
        int c = wc * 64 + nf * 16 + fr;
        offB[nf] = c * 128 + ((fk ^ (c & 7)) << 4);
    }

    // A staging sources from p8 (advance 64 shorts per staged tile)
    auto mkA = [&](int mh, int rho) {
        int dc = rho * 1024 + mh * 512 + w * 64 + lane;  // dest chunk in A region
        int r = dc >> 3, s = dc & 7, h = s ^ (r & 7);
        int q = 2047 + h * 8 - j0 - r;                   // l0 = 0
        int srow = q & 7;
        return p8 + srow * PROW + (q - srow);
    };
    const short* srcA0_0 = mkA(0, 0); const short* srcA0_1 = mkA(0, 1);
    const short* srcA1_0 = mkA(1, 0); const short* srcA1_1 = mkA(1, 1);

    // B staging sources from vtile (advance 16384 shorts = 1 tile per stage)
    const short* vb = vtile + ((size_t)((n * 4 + cm) * NT)) * 2048 * 8;
    const short* srcB0_0 = vb + ((w) * 64 + lane) * 8;
    const short* srcB0_1 = vb + ((w + 8) * 64 + lane) * 8;
    const short* srcB1_0 = vb + (1024 + (w) * 64 + lane) * 8;
    const short* srcB1_1 = vb + (1024 + (w + 8) * 64 + lane) * 8;

    const int dA0 = w * 1024, dA1 = 16384 + w * 1024;
    const int dB0 = 32768 + (w >> 2) * 8192 + (w & 3) * 1024;
    const int dB1 = dB0 + 16384;

#define STAGE_A0(base) { gload_lds16(srcA0_0, (char*)lds_ + (base) + dA0); \
                         gload_lds16(srcA0_1, (char*)lds_ + (base) + dA1); \
                         srcA0_0 += 64; srcA0_1 += 64; }
#define STAGE_A1(base) { gload_lds16(srcA1_0, (char*)lds_ + (base) + 8192 + dA0); \
                         gload_lds16(srcA1_1, (char*)lds_ + (base) + 8192 + dA1); \
                         srcA1_0 += 64; srcA1_1 += 64; }
#define STAGE_B0(base) { gload_lds16(srcB0_0, (char*)lds_ + (base) + dB0); \
                         gload_lds16(srcB0_1, (char*)lds_ + (base) + dB1); \
                         srcB0_0 += 16384; srcB0_1 += 16384; }
#define STAGE_B1(base) { gload_lds16(srcB1_0, (char*)lds_ + (base) + 4096 + dB0); \
                         gload_lds16(srcB1_1, (char*)lds_ + (base) + 4096 + dB1); \
                         srcB1_0 += 16384; srcB1_1 += 16384; }
#define BAR()    asm volatile("s_barrier" ::: "memory")
#define LGKM0()  { asm volatile("s_waitcnt lgkmcnt(0)" ::: "memory"); \
                   __builtin_amdgcn_sched_barrier(0); }
#define VMC4()   asm volatile("s_waitcnt vmcnt(4)" ::: "memory")
#define VMC0()   asm volatile("s_waitcnt vmcnt(0)" ::: "memory")

    // ---- prologue: tile0 full + tile1 (A-mh0, B-nh0) ----
    STAGE_A0(0); STAGE_A1(0); STAGE_B0(0); STAGE_B1(0);
    STAGE_A0(65536); STAGE_B0(65536);
    VMC4();   // tile0 fully landed; tile1's 2 halves may be in flight
    BAR();

    f32x4 acc[8][4] = {};
    s16x8 af[4][2], bf0[2][2], bf1[2][2];

    for (int T = 0; T < NT; ++T) {
        const int par = T & 1;
        const char* bR = (const char*)lds_ + par * 65536;
        const int dstN = (par ^ 1) * 65536;   // buffer of tile T+1
        const int dstC = par * 65536;         // buffer of tile T+2

        // ---------- phase 0: (mh0, nh0) ----------
        #pragma unroll
        for (int m = 0; m < 4; ++m) {
            af[m][0] = *(const s16x8*)(bR + offA[m]);
            af[m][1] = *(const s16x8*)(bR + (offA[m] ^ 64));
        }
        #pragma unroll
        for (int nf = 0; nf < 2; ++nf) {
            bf0[nf][0] = *(const s16x8*)(bR + 32768 + offB[nf]);
            bf0[nf][1] = *(const s16x8*)(bR + 32768 + (offB[nf] ^ 64));
        }
        if (T < NT - 1) { STAGE_A1(dstN); }
        BAR(); LGKM0();
        __builtin_amdgcn_s_setprio(1);
        #pragma unroll
        for (int m = 0; m < 4; ++m)
            #pragma unroll
            for (int nf = 0; nf < 2; ++nf)
                #pragma unroll
                for (int ki = 0; ki < 2; ++ki)
                    acc[m][nf] = __builtin_amdgcn_mfma_f32_16x16x32_bf16(
                        af[m][ki], bf0[nf][ki], acc[m][nf], 0, 0, 0);
        __builtin_amdgcn_s_setprio(0);
        BAR();

        // ---------- phase 1: (mh0, nh1) ----------
        #pragma unroll
        for (int nf = 0; nf < 2; ++nf) {
            bf1[nf][0] = *(const s16x8*)(bR + 32768 + offB[2 + nf]);
            bf1[nf][1] = *(const s16x8*)(bR + 32768 + (offB[2 + nf] ^ 64));
        }
        if (T < NT - 1) { STAGE_B1(dstN); }
        BAR(); LGKM0();
        __builtin_amdgcn_s_setprio(1);
        #pragma unroll
        for (int m = 0; m < 4; ++m)
            #pragma unroll
            for (int nf = 0; nf < 2; ++nf)
                #pragma unroll
                for (int ki = 0; ki < 2; ++ki)
                    acc[m][2 + nf] = __builtin_amdgcn_mfma_f32_16x16x32_bf16(
                        af[m][ki], bf1[nf][ki], acc[m][2 + nf], 0, 0, 0);
        __builtin_amdgcn_s_setprio(0);
        BAR();

        // ---------- phase 2: (mh1, nh0) ----------
        #pragma unroll
        for (int m = 0; m < 4; ++m) {
            af[m][0] = *(const s16x8*)(bR + offA[4 + m]);
            af[m][1] = *(const s16x8*)(bR + (offA[4 + m] ^ 64));
        }
        if (T < NT - 2) { STAGE_A0(dstC); }
        BAR(); LGKM0();
        __builtin_amdgcn_s_setprio(1);
        #pragma unroll
        for (int m = 0; m < 4; ++m)
            #pragma unroll
            for (int nf = 0; nf < 2; ++nf)
                #pragma unroll
                for (int ki = 0; ki < 2; ++ki)
                    acc[4 + m][nf] = __builtin_amdgcn_mfma_f32_16x16x32_bf16(
                        af[m][ki], bf0[nf][ki], acc[4 + m][nf], 0, 0, 0);
        __builtin_amdgcn_s_setprio(0);
        BAR();

        // ---------- phase 3: (mh1, nh1) ----------
        if (T < NT - 2) { STAGE_B0(dstC); VMC4(); }
        else            { VMC0(); }
        BAR(); LGKM0();
        __builtin_amdgcn_s_setprio(1);
        #pragma unroll
        for (int m = 0; m < 4; ++m)
            #pragma unroll
            for (int nf = 0; nf < 2; ++nf)
                #pragma unroll
                for (int ki = 0; ki < 2; ++ki)
                    acc[4 + m][2 + nf] = __builtin_amdgcn_mfma_f32_16x16x32_bf16(
                        af[m][ki], bf1[nf][ki], acc[4 + m][2 + nf], 0, 0, 0);
        __builtin_amdgcn_s_setprio(0);
        BAR();
    }

    // ---- epilogue: C/D layout col=lane&15, row=(lane>>4)*4+r ----
    float* outn = out + (size_t)n * L * HD;
    #pragma unroll
    for (int m = 0; m < 8; ++m) {
        const int row = j0 + wr * 128 + m * 16 + fk * 4;
        #pragma unroll
        for (int nf = 0; nf < 4; ++nf) {
            const int col = c0 + wc * 64 + nf * 16 + fr;
            #pragma unroll
            for (int r = 0; r < 4; ++r)
                outn[(size_t)(row + r) * HD + col] = acc[m][nf][r];
        }
    }
}

// ---- z[j] = S[j] + S[2047-j] - w[0] via 1-block prefix scan ----
__global__ __launch_bounds__(256) void pb_z(const float* __restrict__ w,
                                            float* __restrict__ z) {
    __shared__ float part[256];
    __shared__ float S[L];
    const int t = threadIdx.x;
    float loc[8]; float s = 0.f;
    #pragma unroll
    for (int i = 0; i < 8; ++i) { loc[i] = w[t * 8 + i]; s += loc[i]; }
    part[t] = s;
    __syncthreads();
    if (t == 0) {
        float a = 0.f;
        for (int i = 0; i < 256; ++i) { float tmp = part[i]; part[i] = a; a += tmp; }
    }
    __syncthreads();
    float a = part[t];
    #pragma unroll
    for (int i = 0; i < 8; ++i) { a += loc[i]; S[t * 8 + i] = a; }
    __syncthreads();
    const float w0 = S[0];
    #pragma unroll
    for (int i = 0; i < 8; ++i) {
        int j = t * 8 + i;
        z[j] = S[j] + S[2047 - j] - w0;
    }
}

extern "C" void kernel_launch(void* const* d_in, const int* in_sizes, int n_in,
                              void* d_out, int out_size, void* d_ws, size_t ws_size,
                              hipStream_t stream) {
    const float* v = (const float*)d_in[0];
    const float* w = (const float*)d_in[1];
    float* out = (float*)d_out;

    short* p8    = (short*)d_ws;                       // 64 KB
    short* vtile = (short*)((char*)d_ws + 65536);      // 32 MB

    pb_prep<<<128, 256, 0, stream>>>(w, p8);
    pb_vtile<<<dim3(NT, 4, NB), 256, 0, stream>>>(v, (s16x8*)vtile);
    pb_gemm8<<<256, 512, 0, stream>>>(p8, vtile, out);
    pb_z<<<1, 256, 0, stream>>>(w, out + (size_t)NB * L * HD);
}

// Round 5
// 81.584 us; speedup vs baseline: 2.3452x; 1.0712x over previous
//
#include <hip/hip_runtime.h>
#include <hip/hip_bf16.h>

#define L 2048
#define HD 1024   // H*D
#define NB 8      // batch
#define NT 32     // K tiles of BK=64
#define PROW 4096 // p8 row length

using f32x4 = __attribute__((ext_vector_type(4))) float;
using fl4   = __attribute__((ext_vector_type(4))) float;
using s16x8 = __attribute__((ext_vector_type(8))) short;

__device__ __forceinline__ short f2bf(float f) {
    __hip_bfloat16 h = __float2bfloat16(f);
    short s;
    __builtin_memcpy(&s, &h, 2);
    return s;
}

__device__ __forceinline__ void gload_lds16(const void* g, void* l) {
    __builtin_amdgcn_global_load_lds(
        (const __attribute__((address_space(1))) unsigned int*)g,
        (__attribute__((address_space(3))) unsigned int*)l, 16, 0, 0);
}

// ---- p8[s][x] = bf16(p[x+s]), p[k] = w[|k-2047|] ----
__global__ __launch_bounds__(256) void pb_prep(const float* __restrict__ w,
                                               short* __restrict__ p8) {
    int idx = blockIdx.x * 256 + threadIdx.x;
    int s = idx >> 12;
    int x = idx & (PROW - 1);
    int k = x + s;
    short val = 0;
    if (k <= 4094) {
        int d = k - 2047; d = d < 0 ? -d : d;
        val = f2bf(w[d]);
    }
    p8[idx] = val;
}

// ---- vtile[n][cm][kk] : 2048 chunks of 16B in exact gemm-stage order ----
__global__ __launch_bounds__(256) void pb_vtile(const float* __restrict__ v,
                                                s16x8* __restrict__ vtile) {
    // Ts: (c,l) stored at c*64 + ((l>>3) ^ ((c>>2)&7))*8 + (l&7)  (slot swizzle)
    __shared__ __align__(16) short Ts[256 * 64];   // 32 KB
    const int kk = blockIdx.x, cm = blockIdx.y, n = blockIdx.z;
    const int l0 = kk * 64, c0 = cm * 256;
    const int t = threadIdx.x;
    const float* vn = v + (size_t)n * L * HD;

    #pragma unroll
    for (int i = 0; i < 16; ++i) {
        int unit = i * 256 + t;          // 4096 units = 64 l x 64 quads
        int l = unit >> 6, cq = unit & 63;
        fl4 x = *(const fl4*)&vn[(size_t)(l0 + l) * HD + c0 + cq * 4];
        int lsub = l & 7, lblk = l >> 3;
        #pragma unroll
        for (int j = 0; j < 4; ++j) {
            int c = cq * 4 + j;
            Ts[c * 64 + ((lblk ^ ((c >> 2) & 7)) << 3) + lsub] = f2bf(x[j]);
        }
    }
    __syncthreads();

    s16x8* outtile = vtile + ((size_t)((n * 4 + cm) * NT + kk)) * 2048;
    #pragma unroll
    for (int i2 = 0; i2 < 8; ++i2) {
        int ci = i2 * 256 + t;
        int nh = ci >> 10, cih = ci & 1023;
        int seg = cih >> 8, o = cih & 255;
        int c = seg * 64 + nh * 32 + (o >> 3), s = o & 7;
        int h = s ^ (c & 7);
        int slot = h ^ ((c >> 2) & 7);
        outtile[ci] = *(const s16x8*)&Ts[c * 64 + slot * 8];
    }
}

// ---- main GEMM: 256x256 tile, BK=64, 8 waves, full-tile dbuf, barrier-free tiles ----
__global__ __launch_bounds__(512, 2) void pb_gemm8(const short* __restrict__ p8,
                                                   const short* __restrict__ vtile,
                                                   float* __restrict__ out) {
    __shared__ __align__(16) short lds_[65536];  // 128 KB: 2 bufs x (A 32K | B 32K)

    const int bid = blockIdx.x;
    const int cmn = bid & 31;          // same (n,cm) for all 8 jm -> same XCD
    const int jm  = bid >> 5;
    const int cm  = cmn & 3;
    const int n   = cmn >> 2;
    const int j0 = jm * 256;
    const int c0 = cm * 256;

    const int t = threadIdx.x;
    const int lane = t & 63;
    const int w = t >> 6;              // wave 0..7
    const int wr = w >> 2, wc = w & 3; // 2 x 4 wave grid; wave tile 128x64
    const int fr = lane & 15, fk = lane >> 4;

    // K-invariant LDS read byte-offsets (ki=1 via ^64)
    int offA[8], offB[4];
    #pragma unroll
    for (int m = 0; m < 8; ++m) {
        int r = wr * 128 + m * 16 + fr;
        offA[m] = r * 128 + ((fk ^ (r & 7)) << 4);
    }
    #pragma unroll
    for (int nf = 0; nf < 4; ++nf) {
        int c = wc * 64 + nf * 16 + fr;
        offB[nf] = c * 128 + ((fk ^ (c & 7)) << 4);
    }

    // A staging sources from p8 (advance 64 shorts per tile)
    auto mkA = [&](int mh, int rho) {
        int dc = rho * 1024 + mh * 512 + w * 64 + lane;  // dest chunk in A region
        int r = dc >> 3, s = dc & 7, h = s ^ (r & 7);
        int q = 2047 + h * 8 - j0 - r;                   // l0 = 0
        int srow = q & 7;
        return p8 + srow * PROW + (q - srow);
    };
    const short* srcA0_0 = mkA(0, 0); const short* srcA0_1 = mkA(0, 1);
    const short* srcA1_0 = mkA(1, 0); const short* srcA1_1 = mkA(1, 1);

    // B staging sources from vtile (advance 16384 shorts = 1 tile per stage)
    const short* vb = vtile + ((size_t)((n * 4 + cm) * NT)) * 2048 * 8;
    const short* srcB0_0 = vb + ((w) * 64 + lane) * 8;
    const short* srcB0_1 = vb + ((w + 8) * 64 + lane) * 8;
    const short* srcB1_0 = vb + (1024 + (w) * 64 + lane) * 8;
    const short* srcB1_1 = vb + (1024 + (w + 8) * 64 + lane) * 8;

    const int dA0 = w * 1024, dA1 = 16384 + w * 1024;
    const int dB0 = 32768 + (w >> 2) * 8192 + (w & 3) * 1024;
    const int dB1 = dB0 + 16384;

#define STAGE_ALL(base) { \
    gload_lds16(srcA0_0, (char*)lds_ + (base) + dA0); \
    gload_lds16(srcA0_1, (char*)lds_ + (base) + dA1); \
    gload_lds16(srcA1_0, (char*)lds_ + (base) + 8192 + dA0); \
    gload_lds16(srcA1_1, (char*)lds_ + (base) + 8192 + dA1); \
    gload_lds16(srcB0_0, (char*)lds_ + (base) + dB0); \
    gload_lds16(srcB0_1, (char*)lds_ + (base) + dB1); \
    gload_lds16(srcB1_0, (char*)lds_ + (base) + 4096 + dB0); \
    gload_lds16(srcB1_1, (char*)lds_ + (base) + 4096 + dB1); \
    srcA0_0 += 64; srcA0_1 += 64; srcA1_0 += 64; srcA1_1 += 64; \
    srcB0_0 += 16384; srcB0_1 += 16384; srcB1_0 += 16384; srcB1_1 += 16384; }

    // ---- prologue: tile 0 into buf0 ----
    STAGE_ALL(0);
    __syncthreads();

    f32x4 acc[8][4] = {};

    for (int T = 0; T < NT; ++T) {
        const char* bR = (const char*)lds_ + (T & 1) * 65536;

        // stage tile T+1 entirely into the other buffer (its readers
        // finished at the tile T-1 boundary barrier; no region of bR is
        // written during tile T -> no intra-tile barriers needed)
        if (T < NT - 1) {
            const int nb = ((T + 1) & 1) * 65536;
            STAGE_ALL(nb);
        }

        s16x8 af[4][2], bf0[2][2], bf1[2][2];

        // ---- quadrant (mh0, nh0) ----
        #pragma unroll
        for (int m = 0; m < 4; ++m) {
            af[m][0] = *(const s16x8*)(bR + offA[m]);
            af[m][1] = *(const s16x8*)(bR + (offA[m] ^ 64));
        }
        #pragma unroll
        for (int nf = 0; nf < 2; ++nf) {
            bf0[nf][0] = *(const s16x8*)(bR + 32768 + offB[nf]);
            bf0[nf][1] = *(const s16x8*)(bR + 32768 + (offB[nf] ^ 64));
        }
        #pragma unroll
        for (int m = 0; m < 4; ++m)
            #pragma unroll
            for (int nf = 0; nf < 2; ++nf)
                #pragma unroll
                for (int ki = 0; ki < 2; ++ki)
                    acc[m][nf] = __builtin_amdgcn_mfma_f32_16x16x32_bf16(
                        af[m][ki], bf0[nf][ki], acc[m][nf], 0, 0, 0);

        // ---- quadrant (mh0, nh1) ----
        #pragma unroll
        for (int nf = 0; nf < 2; ++nf) {
            bf1[nf][0] = *(const s16x8*)(bR + 32768 + offB[2 + nf]);
            bf1[nf][1] = *(const s16x8*)(bR + 32768 + (offB[2 + nf] ^ 64));
        }
        #pragma unroll
        for (int m = 0; m < 4; ++m)
            #pragma unroll
            for (int nf = 0; nf < 2; ++nf)
                #pragma unroll
                for (int ki = 0; ki < 2; ++ki)
                    acc[m][2 + nf] = __builtin_amdgcn_mfma_f32_16x16x32_bf16(
                        af[m][ki], bf1[nf][ki], acc[m][2 + nf], 0, 0, 0);

        // ---- quadrant (mh1, nh0) ----
        #pragma unroll
        for (int m = 0; m < 4; ++m) {
            af[m][0] = *(const s16x8*)(bR + offA[4 + m]);
            af[m][1] = *(const s16x8*)(bR + (offA[4 + m] ^ 64));
        }
        #pragma unroll
        for (int m = 0; m < 4; ++m)
            #pragma unroll
            for (int nf = 0; nf < 2; ++nf)
                #pragma unroll
                for (int ki = 0; ki < 2; ++ki)
                    acc[4 + m][nf] = __builtin_amdgcn_mfma_f32_16x16x32_bf16(
                        af[m][ki], bf0[nf][ki], acc[4 + m][nf], 0, 0, 0);

        // ---- quadrant (mh1, nh1) ----
        #pragma unroll
        for (int m = 0; m < 4; ++m)
            #pragma unroll
            for (int nf = 0; nf < 2; ++nf)
                #pragma unroll
                for (int ki = 0; ki < 2; ++ki)
                    acc[4 + m][2 + nf] = __builtin_amdgcn_mfma_f32_16x16x32_bf16(
                        af[m][ki], bf1[nf][ki], acc[4 + m][2 + nf], 0, 0, 0);

        // tile boundary: drains vmcnt (tile T+1 staged) + orders reads vs
        // the tile T+2 stage writes issued next iteration
        __syncthreads();
    }

    // ---- epilogue: C/D layout col=lane&15, row=(lane>>4)*4+r ----
    float* outn = out + (size_t)n * L * HD;
    #pragma unroll
    for (int m = 0; m < 8; ++m) {
        const int row = j0 + wr * 128 + m * 16 + fk * 4;
        #pragma unroll
        for (int nf = 0; nf < 4; ++nf) {
            const int col = c0 + wc * 64 + nf * 16 + fr;
            #pragma unroll
            for (int r = 0; r < 4; ++r)
                outn[(size_t)(row + r) * HD + col] = acc[m][nf][r];
        }
    }
}

// ---- z[j] = S[j] + S[2047-j] - w[0] via 1-block prefix scan ----
__global__ __launch_bounds__(256) void pb_z(const float* __restrict__ w,
                                            float* __restrict__ z) {
    __shared__ float part[256];
    __shared__ float S[L];
    const int t = threadIdx.x;
    float loc[8]; float s = 0.f;
    #pragma unroll
    for (int i = 0; i < 8; ++i) { loc[i] = w[t * 8 + i]; s += loc[i]; }
    part[t] = s;
    __syncthreads();
    if (t == 0) {
        float a = 0.f;
        for (int i = 0; i < 256; ++i) { float tmp = part[i]; part[i] = a; a += tmp; }
    }
    __syncthreads();
    float a = part[t];
    #pragma unroll
    for (int i = 0; i < 8; ++i) { a += loc[i]; S[t * 8 + i] = a; }
    __syncthreads();
    const float w0 = S[0];
    #pragma unroll
    for (int i = 0; i < 8; ++i) {
        int j = t * 8 + i;
        z[j] = S[j] + S[2047 - j] - w0;
    }
}

extern "C" void kernel_launch(void* const* d_in, const int* in_sizes, int n_in,
                              void* d_out, int out_size, void* d_ws, size_t ws_size,
                              hipStream_t stream) {
    const float* v = (const float*)d_in[0];
    const float* w = (const float*)d_in[1];
    float* out = (float*)d_out;

    short* p8    = (short*)d_ws;                       // 64 KB
    short* vtile = (short*)((char*)d_ws + 65536);      // 32 MB

    pb_prep<<<128, 256, 0, stream>>>(w, p8);
    pb_vtile<<<dim3(NT, 4, NB), 256, 0, stream>>>(v, (s16x8*)vtile);
    pb_gemm8<<<256, 512, 0, stream>>>(p8, vtile, out);
    pb_z<<<1, 256, 0, stream>>>(w, out + (size_t)NB * L * HD);
}